// Round 1
// baseline (339.335 us; speedup 1.0000x reference)
//
#include <hip/hip_runtime.h>
#include <hip/hip_bf16.h>

#define AS1 __attribute__((address_space(1)))
#define AS3 __attribute__((address_space(3)))

typedef __attribute__((ext_vector_type(8))) short bfrag8;   // 8 bf16 in 4 VGPRs
typedef __attribute__((ext_vector_type(4))) float floatx4;  // MFMA accumulator

static constexpr int M = 4096, N = 4096, K = 4096;
static constexpr long long NELEM = 16777216LL;   // 4096*4096 (both x and W)
static constexpr int PB = 1024;                  // prep blocks per array

// ---------- round-to-nearest-even fp32 -> bf16 ----------
__device__ __forceinline__ unsigned short f2bf(float f) {
    unsigned int u = __float_as_uint(f);
    u += 0x7FFFu + ((u >> 16) & 1u);
    return (unsigned short)(u >> 16);
}

// ---------- ternary quantize: bf16 {-1,0,+1}; exact fp32 division as reference ----------
__device__ __forceinline__ unsigned short tq(float v, float scale_f) {
    float wn = v / scale_f;
    if (fabsf(wn) > 0.5f)
        return (unsigned short)(0x3F80u | ((__float_as_uint(v) >> 16) & 0x8000u));
    return 0;
}

// ---------- block reduce (double) -> value on thread 0 ----------
__device__ __forceinline__ double block_reduce(double s) {
    #pragma unroll
    for (int off = 32; off > 0; off >>= 1) s += __shfl_down(s, off, 64);
    __shared__ double part[4];
    int lane = threadIdx.x & 63, wv = threadIdx.x >> 6;
    if (lane == 0) part[wv] = s;
    __syncthreads();
    return part[0] + part[1] + part[2] + part[3];
}

// ---------- dual block reduce (double), broadcast result to ALL threads ----------
__device__ __forceinline__ void block_reduce2_bcast(double& a, double& b) {
    #pragma unroll
    for (int off = 32; off > 0; off >>= 1) {
        a += __shfl_down(a, off, 64);
        b += __shfl_down(b, off, 64);
    }
    __shared__ double pa[4], pb[4];
    int lane = threadIdx.x & 63, wv = threadIdx.x >> 6;
    if (lane == 0) { pa[wv] = a; pb[wv] = b; }
    __syncthreads();
    a = pa[0] + pa[1] + pa[2] + pa[3];
    b = pb[0] + pb[1] + pb[2] + pb[3];
}

// ---------- prep: blocks [0,PB) -> sum|x| + x->bf16 ; [PB,2PB) -> sum|w| ----------
__global__ __launch_bounds__(256) void prep_reduce(
        const float* __restrict__ x, unsigned short* __restrict__ xb,
        const float* __restrict__ w,
        double* __restrict__ px, double* __restrict__ pw) {
    const int b = blockIdx.x;
    const bool isW = b >= PB;
    const int rb = isW ? b - PB : b;
    const float4* src = (const float4*)(isW ? w : x);
    const long long base = (long long)rb * 4096 + threadIdx.x;  // float4 index

    float4 v[16];
    #pragma unroll
    for (int i = 0; i < 16; i++) v[i] = src[base + i * 256];    // 16 independent loads

    double s = 0.0;
    #pragma unroll
    for (int i = 0; i < 16; i++) {
        s += (double)fabsf(v[i].x); s += (double)fabsf(v[i].y);
        s += (double)fabsf(v[i].z); s += (double)fabsf(v[i].w);
    }

    if (!isW) {
        ushort4* xb4 = (ushort4*)xb;
        #pragma unroll
        for (int i = 0; i < 16; i++) {
            ushort4 r;
            r.x = f2bf(v[i].x); r.y = f2bf(v[i].y);
            r.z = f2bf(v[i].z); r.w = f2bf(v[i].w);
            xb4[base + i * 256] = r;
        }
    }

    double bs = block_reduce(s);
    if (threadIdx.x == 0) (isW ? pw : px)[rb] = bs;
}

// ---------- quantize w (block-contiguous) + inline scale finalize ----------
__global__ __launch_bounds__(256) void quantize_w(
        const float* __restrict__ w, unsigned short* __restrict__ qb,
        const double* __restrict__ px, const double* __restrict__ pw,
        float* __restrict__ scales) {
    const int t = threadIdx.x;
    double sx = 0.0, sw = 0.0;
    #pragma unroll
    for (int i = 0; i < 4; i++) { sx += px[t + i * 256]; sw += pw[t + i * 256]; }
    block_reduce2_bcast(sx, sw);
    const float scale_w = (float)fmax(sw / (double)NELEM, 1e-8);
    const float scale_x = (float)fmax(sx / (double)NELEM, 1e-8);
    if (blockIdx.x == 0 && t == 0) { scales[0] = scale_w; scales[1] = scale_x; }

    const float4* w4 = (const float4*)w;
    ushort4* q4 = (ushort4*)qb;
    const long long base = (long long)blockIdx.x * 4096 + t;
    float4 v[16];
    #pragma unroll
    for (int i = 0; i < 16; i++) v[i] = w4[base + i * 256];
    #pragma unroll
    for (int i = 0; i < 16; i++) {
        ushort4 r;
        r.x = tq(v[i].x, scale_w); r.y = tq(v[i].y, scale_w);
        r.z = tq(v[i].z, scale_w); r.w = tq(v[i].w, scale_w);
        q4[base + i * 256] = r;
    }
}

// ---------- R6: 256x256 tile, BK=64, 8-wave, 8-phase schedule (HK-style, plain HIP) ----------
// Per wave: 128x64 output = acc[8][4] floatx4. LDS: 2 buffers x (A 32KB + B 32KB) = 128KB.
// Each K-tile = 4 phases; phase = {ds_read A-subtile (+B at q0), issue stage, raw barrier,
// lgkmcnt(0), setprio(1)+16 MFMA+setprio(0), [vmcnt(0) at q3], raw barrier}.
// Only one vmcnt wait per K-tile; its loads were issued 2-3 phases earlier (counted-age idiom).
// XOR-chunk LDS swizzle (slot = chunk ^ (row&7)) on both stage-source and read side:
// SQ_LDS_BANK_CONFLICT = 0 verified with this exact pattern in R2/R3.
// Summation order per output element identical to R5 kernel -> bitwise-same result.
__global__ __launch_bounds__(512, 2) void gemm_bt256(
        const unsigned short* __restrict__ A,
        const unsigned short* __restrict__ B,
        const float* __restrict__ bias,
        const float* __restrict__ scales,   // [0]=wscale, [1]=iscale
        float* __restrict__ out) {
    __shared__ alignas(16) char lds[131072];

    const int tid = threadIdx.x;
    const int lane = tid & 63;
    const int wv = tid >> 6;            // 0..7
    const int wm = wv & 1;              // 2 M-waves (128 rows each)
    const int wn = wv >> 1;             // 4 N-waves (64 cols each)
    const int col16 = lane & 15;
    const int quad  = lane >> 4;

    // XCD-bijective swizzle: 256 blocks = 8 XCD chunks x 32; each XCD gets a 2x16 tile rect
    const int bid = blockIdx.x;
    const int swz = (bid & 7) * 32 + (bid >> 3);
    const int bx = swz & 15;            // n-tile
    const int by = swz >> 4;            // m-tile
    const int m0 = by * 256;
    const int n0 = bx * 256;

    // staging constants (pre-swizzled global source, linear LDS dest)
    const int srow8  = lane >> 3;            // row within 8-row group
    const int schunk = (lane & 7) ^ srow8;   // k-chunk this lane fetches
    const int scol   = schunk * 8;           // element offset

    floatx4 acc[8][4];
    #pragma unroll
    for (int i = 0; i < 8; i++)
        #pragma unroll
        for (int j = 0; j < 4; j++)
            acc[i][j] = (floatx4)0.0f;

    char* ldsc = (char*)lds;

    // stage one 256x64 matrix tile: 4 global_load_lds per thread (2 halves x 2)
    auto stage4 = [&](const unsigned short* __restrict__ gmat, int base0,
                      char* region, long long k0) {
        #pragma unroll
        for (int h = 0; h < 2; ++h)
            #pragma unroll
            for (int l = 0; l < 2; ++l) {
                const int c = wv * 2 + l;                       // 0..15 within half
                const unsigned short* g = gmat
                    + (size_t)(base0 + h * 128 + c * 8 + srow8) * (size_t)K
                    + (size_t)k0 + scol;
                char* d = region + h * 16384 + c * 1024 + lane * 16;
                __builtin_amdgcn_global_load_lds((const AS1 void*)g, (AS3 void*)d, 16, 0, 0);
            }
    };

    // ---- prologue: tile0 -> buf0, tile1 -> buf1; wait tile0 (8 newest stay in flight) ----
    stage4(A, m0, ldsc,                 0);
    stage4(B, n0, ldsc + 32768,         0);
    stage4(A, m0, ldsc + 65536,         64);
    stage4(B, n0, ldsc + 65536 + 32768, 64);
    asm volatile("s_waitcnt vmcnt(8)" ::: "memory");
    __builtin_amdgcn_s_barrier();

    // ---- one K-tile: 4 quadrant phases ----
    auto tile_body = [&](const char* bufc, char* bufn, int t) {
        const bool doStage = (t >= 1) && (t < 63);
        const long long knext = (long long)(t + 1) * 64;
        const char* bA = bufc;
        const char* bB = bufc + 32768;

        // B fragments for the whole tile (8 x ds_read_b128), held in regs
        bfrag8 bf[4][2];
        #pragma unroll
        for (int j = 0; j < 4; ++j) {
            const int rB = wn * 64 + j * 16 + col16;
            #pragma unroll
            for (int kk = 0; kk < 2; ++kk)
                bf[j][kk] = *(const bfrag8*)(bB + rB * 128 +
                                (((kk * 4 + quad) ^ (col16 & 7)) << 4));
        }

        #pragma unroll
        for (int q = 0; q < 4; ++q) {
            bfrag8 af[2][2];
            #pragma unroll
            for (int di = 0; di < 2; ++di) {
                const int rA = wm * 128 + (q * 2 + di) * 16 + col16;
                #pragma unroll
                for (int kk = 0; kk < 2; ++kk)
                    af[di][kk] = *(const bfrag8*)(bA + rA * 128 +
                                    (((kk * 4 + quad) ^ (col16 & 7)) << 4));
            }
            if (q == 0 && doStage) stage4(B, n0, bufn + 32768, knext);
            if (q == 1 && doStage) stage4(A, m0, bufn, knext);

            __builtin_amdgcn_s_barrier();
            asm volatile("s_waitcnt lgkmcnt(0)" ::: "memory");
            __builtin_amdgcn_s_setprio(1);
            #pragma unroll
            for (int di = 0; di < 2; ++di)
                #pragma unroll
                for (int j = 0; j < 4; ++j) {
                    acc[q * 2 + di][j] = __builtin_amdgcn_mfma_f32_16x16x32_bf16(
                        af[di][0], bf[j][0], acc[q * 2 + di][j], 0, 0, 0);
                    acc[q * 2 + di][j] = __builtin_amdgcn_mfma_f32_16x16x32_bf16(
                        af[di][1], bf[j][1], acc[q * 2 + di][j], 0, 0, 0);
                }
            __builtin_amdgcn_s_setprio(0);
            if (q == 3) asm volatile("s_waitcnt vmcnt(0)" ::: "memory");
            __builtin_amdgcn_s_barrier();
        }
    };

    // ---- main loop: 2 K-tiles per iteration (compile-time buffer bases) ----
    for (int t2 = 0; t2 < 32; ++t2) {
        tile_body(ldsc,         ldsc + 65536, 2 * t2);
        tile_body(ldsc + 65536, ldsc,         2 * t2 + 1);
    }

    // ---- epilogue ----
    const float wscale = scales[0];
    const float iscale = scales[1];

    float bv[4];
    #pragma unroll
    for (int j = 0; j < 4; ++j)
        bv[j] = bias[n0 + wn * 64 + j * 16 + col16] * iscale;

    #pragma unroll
    for (int i = 0; i < 8; ++i) {
        const int mbase = m0 + wm * 128 + i * 16 + quad * 4;
        #pragma unroll
        for (int j = 0; j < 4; ++j) {
            const int n = n0 + wn * 64 + j * 16 + col16;
            #pragma unroll
            for (int r = 0; r < 4; ++r)
                out[(size_t)(mbase + r) * N + n] = acc[i][j][r] * wscale + bv[j];
        }
    }
}

extern "C" void kernel_launch(void* const* d_in, const int* in_sizes, int n_in,
                              void* d_out, int out_size, void* d_ws, size_t ws_size,
                              hipStream_t stream) {
    const float* x    = (const float*)d_in[0];   // (2,2048,4096) fp32
    const float* w    = (const float*)d_in[1];   // (4096,4096) fp32
    const float* bias = (const float*)d_in[2];   // (4096,) fp32
    float* out = (float*)d_out;                  // (2,2048,4096) fp32

    char* ws = (char*)d_ws;
    float*  scales = (float*)ws;                       // 16 B
    double* px     = (double*)(ws + 256);              // 1024 doubles (8 KB)
    double* pw     = (double*)(ws + 256 + PB * 8);     // 1024 doubles (8 KB)
    unsigned short* xb = (unsigned short*)(ws + 16640);                      // 32 MB bf16 x
    unsigned short* qb = (unsigned short*)(ws + 16640 + (size_t)NELEM * 2);  // 32 MB bf16 qW

    prep_reduce<<<2 * PB, 256, 0, stream>>>(x, xb, w, px, pw);
    quantize_w<<<PB, 256, 0, stream>>>(w, qb, px, pw, scales);

    gemm_bt256<<<dim3(256), 512, 0, stream>>>(xb, qb, bias, scales, out);
}

// Round 2
// 287.481 us; speedup vs baseline: 1.1804x; 1.1804x over previous
//
#include <hip/hip_runtime.h>
#include <hip/hip_bf16.h>

#define AS1 __attribute__((address_space(1)))
#define AS3 __attribute__((address_space(3)))

typedef __attribute__((ext_vector_type(8))) short bfrag8;   // 8 bf16 in 4 VGPRs
typedef __attribute__((ext_vector_type(4))) float floatx4;  // MFMA accumulator

static constexpr int M = 4096, N = 4096, K = 4096;
static constexpr long long NELEM = 16777216LL;   // 4096*4096 (both x and W)
static constexpr int PB = 1024;                  // prep blocks per array

// ---------- round-to-nearest-even fp32 -> bf16 ----------
__device__ __forceinline__ unsigned short f2bf(float f) {
    unsigned int u = __float_as_uint(f);
    u += 0x7FFFu + ((u >> 16) & 1u);
    return (unsigned short)(u >> 16);
}

// ---------- ternary quantize: bf16 {-1,0,+1}; exact fp32 division as reference ----------
__device__ __forceinline__ unsigned short tq(float v, float scale_f) {
    float wn = v / scale_f;
    if (fabsf(wn) > 0.5f)
        return (unsigned short)(0x3F80u | ((__float_as_uint(v) >> 16) & 0x8000u));
    return 0;
}

// ---------- block reduce (double) -> value on thread 0 ----------
__device__ __forceinline__ double block_reduce(double s) {
    #pragma unroll
    for (int off = 32; off > 0; off >>= 1) s += __shfl_down(s, off, 64);
    __shared__ double part[4];
    int lane = threadIdx.x & 63, wv = threadIdx.x >> 6;
    if (lane == 0) part[wv] = s;
    __syncthreads();
    return part[0] + part[1] + part[2] + part[3];
}

// ---------- dual block reduce (double), broadcast result to ALL threads ----------
__device__ __forceinline__ void block_reduce2_bcast(double& a, double& b) {
    #pragma unroll
    for (int off = 32; off > 0; off >>= 1) {
        a += __shfl_down(a, off, 64);
        b += __shfl_down(b, off, 64);
    }
    __shared__ double pa[4], pb[4];
    int lane = threadIdx.x & 63, wv = threadIdx.x >> 6;
    if (lane == 0) { pa[wv] = a; pb[wv] = b; }
    __syncthreads();
    a = pa[0] + pa[1] + pa[2] + pa[3];
    b = pb[0] + pb[1] + pb[2] + pb[3];
}

// ---------- prep: blocks [0,PB) -> sum|x| + x->bf16 ; [PB,2PB) -> sum|w| ----------
__global__ __launch_bounds__(256) void prep_reduce(
        const float* __restrict__ x, unsigned short* __restrict__ xb,
        const float* __restrict__ w,
        double* __restrict__ px, double* __restrict__ pw) {
    const int b = blockIdx.x;
    const bool isW = b >= PB;
    const int rb = isW ? b - PB : b;
    const float4* src = (const float4*)(isW ? w : x);
    const long long base = (long long)rb * 4096 + threadIdx.x;  // float4 index

    float4 v[16];
    #pragma unroll
    for (int i = 0; i < 16; i++) v[i] = src[base + i * 256];    // 16 independent loads

    double s = 0.0;
    #pragma unroll
    for (int i = 0; i < 16; i++) {
        s += (double)fabsf(v[i].x); s += (double)fabsf(v[i].y);
        s += (double)fabsf(v[i].z); s += (double)fabsf(v[i].w);
    }

    if (!isW) {
        ushort4* xb4 = (ushort4*)xb;
        #pragma unroll
        for (int i = 0; i < 16; i++) {
            ushort4 r;
            r.x = f2bf(v[i].x); r.y = f2bf(v[i].y);
            r.z = f2bf(v[i].z); r.w = f2bf(v[i].w);
            xb4[base + i * 256] = r;
        }
    }

    double bs = block_reduce(s);
    if (threadIdx.x == 0) (isW ? pw : px)[rb] = bs;
}

// ---------- quantize w (block-contiguous) + inline scale finalize ----------
__global__ __launch_bounds__(256) void quantize_w(
        const float* __restrict__ w, unsigned short* __restrict__ qb,
        const double* __restrict__ px, const double* __restrict__ pw,
        float* __restrict__ scales) {
    const int t = threadIdx.x;
    double sx = 0.0, sw = 0.0;
    #pragma unroll
    for (int i = 0; i < 4; i++) { sx += px[t + i * 256]; sw += pw[t + i * 256]; }
    block_reduce2_bcast(sx, sw);
    const float scale_w = (float)fmax(sw / (double)NELEM, 1e-8);
    const float scale_x = (float)fmax(sx / (double)NELEM, 1e-8);
    if (blockIdx.x == 0 && t == 0) { scales[0] = scale_w; scales[1] = scale_x; }

    const float4* w4 = (const float4*)w;
    ushort4* q4 = (ushort4*)qb;
    const long long base = (long long)blockIdx.x * 4096 + t;
    float4 v[16];
    #pragma unroll
    for (int i = 0; i < 16; i++) v[i] = w4[base + i * 256];
    #pragma unroll
    for (int i = 0; i < 16; i++) {
        ushort4 r;
        r.x = tq(v[i].x, scale_w); r.y = tq(v[i].y, scale_w);
        r.z = tq(v[i].z, scale_w); r.w = tq(v[i].w, scale_w);
        q4[base + i * 256] = r;
    }
}

// ---------- R7: 256x256 / BK=64 / 8-wave, COUNTED-vmcnt pipeline (T3+T4 fixed) ----------
// R6 bug: drained vmcnt(0) each K-tile -> 8-phase-with-drain0 == 1-phase perf (m218).
// Now: stage ONE half-tile (2 loads/thread) per phase; per-tile slot map
//   P1(t): A(t+1).h0 -> other buf   (region last ds_read at P4(t-1), barrier-separated)
//   P2(t): A(t+1).h1 -> other buf
//   P3(t): B(t+2).h0 -> same buf    (B region last ds_read at P1(t), 2 barriers earlier)
//   P4(t): B(t+2).h1 -> same buf;  s_waitcnt vmcnt(4) AFTER MFMA (2 youngest halves stay
//          in flight; everything tile t+1 reads is proven landed). Never vmcnt(0) in loop.
// Cover distance: B halves 5-6 phases (HBM-miss ~900cy OK), A halves 2-4 phases (L2-hit).
// XOR-chunk LDS swizzle unchanged (bank conflicts = 0 verified). MFMA order identical to
// R5/R6 -> bitwise-same output.
__global__ __launch_bounds__(512, 2) void gemm_bt256(
        const unsigned short* __restrict__ A,
        const unsigned short* __restrict__ B,
        const float* __restrict__ bias,
        const float* __restrict__ scales,   // [0]=wscale, [1]=iscale
        float* __restrict__ out) {
    __shared__ alignas(16) char lds[131072];
    // buf layout: buf0 = lds, buf1 = lds+65536. Within a buf: A tile 32KB, B tile 32KB.

    const int tid = threadIdx.x;
    const int lane = tid & 63;
    const int wv = tid >> 6;            // 0..7
    const int wm = wv & 1;              // 2 M-waves (128 rows each)
    const int wn = wv >> 1;             // 4 N-waves (64 cols each)
    const int col16 = lane & 15;
    const int quad  = lane >> 4;

    // XCD-bijective swizzle: 256 blocks = 8 XCD chunks x 32; each XCD a 2x16 tile rect
    const int bid = blockIdx.x;
    const int swz = (bid & 7) * 32 + (bid >> 3);
    const int bx = swz & 15;            // n-tile
    const int by = swz >> 4;            // m-tile
    const int m0 = by * 256;
    const int n0 = bx * 256;

    // staging constants (pre-swizzled global source, linear LDS dest)
    const int srow8  = lane >> 3;            // row within 8-row group
    const int schunk = (lane & 7) ^ srow8;   // k-chunk this lane fetches
    const int scol   = schunk * 8;           // element offset

    floatx4 acc[8][4];
    #pragma unroll
    for (int i = 0; i < 8; i++)
        #pragma unroll
        for (int j = 0; j < 4; j++)
            acc[i][j] = (floatx4)0.0f;

    char* buf0 = (char*)lds;
    char* buf1 = (char*)lds + 65536;

    // stage one half-tile (128 rows x 64 k): 2 global_load_lds per thread
    auto stage_half = [&](const unsigned short* __restrict__ gmat, int base0,
                          char* region, long long k0, int h) {
        #pragma unroll
        for (int l = 0; l < 2; ++l) {
            const int c = wv * 2 + l;                       // 0..15 within half
            const unsigned short* g = gmat
                + (size_t)(base0 + h * 128 + c * 8 + srow8) * (size_t)K
                + (size_t)k0 + scol;
            char* d = region + h * 16384 + c * 1024 + lane * 16;
            __builtin_amdgcn_global_load_lds((const AS1 void*)g, (AS3 void*)d, 16, 0, 0);
        }
    };

    // ---- prologue: tile0 (4 halves) + B(1) (2 halves); wait oldest 8, keep 4 in flight ----
    stage_half(B, n0, buf0 + 32768, 0, 0);
    stage_half(B, n0, buf0 + 32768, 0, 1);
    stage_half(A, m0, buf0,         0, 0);
    stage_half(A, m0, buf0,         0, 1);
    stage_half(B, n0, buf1 + 32768, 64, 0);
    stage_half(B, n0, buf1 + 32768, 64, 1);
    asm volatile("s_waitcnt vmcnt(4)" ::: "memory");
    __builtin_amdgcn_s_barrier();

    // ---- one K-tile: 4 quadrant phases, counted-vmcnt staging ----
    auto tile_body = [&](char* bufc, char* bufn, int t) {
        const bool stA = (t + 1) < 64;
        const bool stB = (t + 2) < 64;
        const long long kA = (long long)(t + 1) * 64;
        const long long kB = (long long)(t + 2) * 64;
        const char* bA = bufc;
        const char* bB = bufc + 32768;

        // B fragments for the whole tile (8 x ds_read_b128), held in regs
        bfrag8 bf[4][2];
        #pragma unroll
        for (int j = 0; j < 4; ++j) {
            const int rB = wn * 64 + j * 16 + col16;
            #pragma unroll
            for (int kk = 0; kk < 2; ++kk)
                bf[j][kk] = *(const bfrag8*)(bB + rB * 128 +
                                (((kk * 4 + quad) ^ (col16 & 7)) << 4));
        }

        #pragma unroll
        for (int q = 0; q < 4; ++q) {
            bfrag8 af[2][2];
            #pragma unroll
            for (int di = 0; di < 2; ++di) {
                const int rA = wm * 128 + (q * 2 + di) * 16 + col16;
                #pragma unroll
                for (int kk = 0; kk < 2; ++kk)
                    af[di][kk] = *(const bfrag8*)(bA + rA * 128 +
                                    (((kk * 4 + quad) ^ (col16 & 7)) << 4));
            }
            // counted-pipeline staging: one half-tile per phase
            if (q == 0 && stA) stage_half(A, m0, bufn, kA, 0);
            if (q == 1 && stA) stage_half(A, m0, bufn, kA, 1);
            if (q == 2 && stB) stage_half(B, n0, bufc + 32768, kB, 0);
            if (q == 3 && stB) stage_half(B, n0, bufc + 32768, kB, 1);

            __builtin_amdgcn_s_barrier();
            asm volatile("s_waitcnt lgkmcnt(0)" ::: "memory");
            __builtin_amdgcn_s_setprio(1);
            #pragma unroll
            for (int di = 0; di < 2; ++di)
                #pragma unroll
                for (int j = 0; j < 4; ++j) {
                    acc[q * 2 + di][j] = __builtin_amdgcn_mfma_f32_16x16x32_bf16(
                        af[di][0], bf[j][0], acc[q * 2 + di][j], 0, 0, 0);
                    acc[q * 2 + di][j] = __builtin_amdgcn_mfma_f32_16x16x32_bf16(
                        af[di][1], bf[j][1], acc[q * 2 + di][j], 0, 0, 0);
                }
            __builtin_amdgcn_s_setprio(0);
            if (q == 3) asm volatile("s_waitcnt vmcnt(4)" ::: "memory");
            __builtin_amdgcn_s_barrier();
        }
    };

    // ---- main loop: 2 K-tiles per iteration (compile-time buffer bases) ----
    for (int t2 = 0; t2 < 32; ++t2) {
        tile_body(buf0, buf1, 2 * t2);
        tile_body(buf1, buf0, 2 * t2 + 1);
    }

    // ---- epilogue ----
    const float wscale = scales[0];
    const float iscale = scales[1];

    float bv[4];
    #pragma unroll
    for (int j = 0; j < 4; ++j)
        bv[j] = bias[n0 + wn * 64 + j * 16 + col16] * iscale;

    #pragma unroll
    for (int i = 0; i < 8; ++i) {
        const int mbase = m0 + wm * 128 + i * 16 + quad * 4;
        #pragma unroll
        for (int j = 0; j < 4; ++j) {
            const int n = n0 + wn * 64 + j * 16 + col16;
            #pragma unroll
            for (int r = 0; r < 4; ++r)
                out[(size_t)(mbase + r) * N + n] = acc[i][j][r] * wscale + bv[j];
        }
    }
}

extern "C" void kernel_launch(void* const* d_in, const int* in_sizes, int n_in,
                              void* d_out, int out_size, void* d_ws, size_t ws_size,
                              hipStream_t stream) {
    const float* x    = (const float*)d_in[0];   // (2,2048,4096) fp32
    const float* w    = (const float*)d_in[1];   // (4096,4096) fp32
    const float* bias = (const float*)d_in[2];   // (4096,) fp32
    float* out = (float*)d_out;                  // (2,2048,4096) fp32

    char* ws = (char*)d_ws;
    float*  scales = (float*)ws;                       // 16 B
    double* px     = (double*)(ws + 256);              // 1024 doubles (8 KB)
    double* pw     = (double*)(ws + 256 + PB * 8);     // 1024 doubles (8 KB)
    unsigned short* xb = (unsigned short*)(ws + 16640);                      // 32 MB bf16 x
    unsigned short* qb = (unsigned short*)(ws + 16640 + (size_t)NELEM * 2);  // 32 MB bf16 qW

    prep_reduce<<<2 * PB, 256, 0, stream>>>(x, xb, w, px, pw);
    quantize_w<<<PB, 256, 0, stream>>>(w, qb, px, pw, scales);

    gemm_bt256<<<dim3(256), 512, 0, stream>>>(xb, qb, bias, scales, out);
}